// Round 2
// baseline (910.638 us; speedup 1.0000x reference)
//
#include <hip/hip_runtime.h>
#include <hip/hip_bf16.h>

#define F_IN   64
#define NN     24
#define HH     64
#define CC     (NN * HH)      // 1536
#define ROWS   8
#define BT_TOT (16 * 2048)    // 32768
#define ALPHA_ 0.2f
#define NEG_INF_ -9.0e15f

// ---------------------------------------------------------------------------
// Precompute: WpWT[c*64+f] = sum_k Wp[f, n*64+k] * W[k, j]   (c = n*64+j)
//             bpW[n*64+j]  = sum_k bp[n*64+k]   * W[k, j]
// ---------------------------------------------------------------------------
__global__ __launch_bounds__(256) void precompute_kernel(
    const float* __restrict__ Wp,
    const float* __restrict__ bp,
    const float* __restrict__ W,
    float* __restrict__ WpWT,
    float* __restrict__ bpW)
{
    int t = blockIdx.x * 256 + threadIdx.x;
    if (t < CC * F_IN) {
        int c = t >> 6, f = t & 63;
        int n = c >> 6, j = c & 63;
        float s = 0.f;
        #pragma unroll 8
        for (int k = 0; k < 64; ++k)
            s += Wp[f * CC + n * 64 + k] * W[k * 64 + j];
        WpWT[t] = s;
    } else {
        int t2 = t - CC * F_IN;
        if (t2 < CC) {
            int n = t2 >> 6, j = t2 & 63;
            float s = 0.f;
            #pragma unroll 8
            for (int k = 0; k < 64; ++k)
                s += bp[n * 64 + k] * W[k * 64 + j];
            bpW[t2] = s;
        }
    }
}

// ---------------------------------------------------------------------------
// Main fused kernel: 8 rows per block of 256 threads.
// ---------------------------------------------------------------------------
__global__ __launch_bounds__(256, 2) void gat_main_kernel(
    const float* __restrict__ x,
    const int* __restrict__ adj,
    const float* __restrict__ a_vec,
    const float* __restrict__ WpWT,
    const float* __restrict__ bpW,
    float* __restrict__ out)
{
    __shared__ float xs[ROWS * F_IN];           // 2 KB
    __shared__ float whs[ROWS * NN * 65];       // 49.9 KB (pad 65 breaks bank aliasing)
    __shared__ float attn_s[ROWS * NN * 25];    // 19.2 KB

    const int tid = threadIdx.x;
    const size_t base = (size_t)blockIdx.x * ROWS;

    // stage x rows (fp32, coalesced)
    for (int i = tid; i < ROWS * F_IN; i += 256)
        xs[i] = x[base * F_IN + i];
    __syncthreads();

    // ---------- Phase 2: Wh tile = x_tile @ WpW + bpW ----------
    // each thread handles 6 columns (2 at a time), all 8 rows.
    for (int q = 0; q < 3; ++q) {
        const int c0 = tid + 512 * q;
        const int c1 = c0 + 256;
        float4 wa[16], wb[16];
        const float4* pa = (const float4*)(WpWT + (size_t)c0 * F_IN);
        const float4* pb = (const float4*)(WpWT + (size_t)c1 * F_IN);
        #pragma unroll
        for (int k = 0; k < 16; ++k) { wa[k] = pa[k]; wb[k] = pb[k]; }
        const float b0 = bpW[c0], b1 = bpW[c1];
        const int n0 = c0 >> 6, j0 = c0 & 63;
        const int n1 = c1 >> 6, j1 = c1 & 63;
        #pragma unroll
        for (int r = 0; r < ROWS; ++r) {
            const float4* xr = (const float4*)(xs + r * F_IN);
            float s0 = 0.f, s1 = 0.f;
            #pragma unroll
            for (int k = 0; k < 16; ++k) {
                float4 xv = xr[k];
                s0 += wa[k].x * xv.x + wa[k].y * xv.y + wa[k].z * xv.z + wa[k].w * xv.w;
                s1 += wb[k].x * xv.x + wb[k].y * xv.y + wb[k].z * xv.z + wb[k].w * xv.w;
            }
            whs[(r * NN + n0) * 65 + j0] = s0 + b0;
            whs[(r * NN + n1) * 65 + j1] = s1 + b1;
        }
    }
    __syncthreads();

    // ---------- Phase 3: attention + ELU + mean, one wave per 2 rows ----------
    const int lane = tid & 63;
    const int wid  = tid >> 6;

    // adjacency bitmask for lanes < 24 (adj is tiny; L2-cached)
    unsigned amask = 0u;
    if (lane < NN) {
        #pragma unroll
        for (int j = 0; j < NN; ++j)
            amask |= (adj[lane * NN + j] > 0 ? 1u : 0u) << j;
    }

    for (int rr = 0; rr < 2; ++rr) {
        const int r = wid * 2 + rr;

        // f1 (lanes 0..23) / f2 (lanes 24..47): dot(Wh_row[n,:], a1/a2)
        float fval = 0.f;
        if (lane < 2 * NN) {
            const int which = (lane >= NN) ? 1 : 0;
            const int n = lane - which * NN;
            const float* wh = whs + (r * NN + n) * 65;
            const float* av = a_vec + which * HH;
            #pragma unroll
            for (int k = 0; k < HH; ++k)
                fval += wh[k] * av[k];
        }

        // e-row, leaky relu, mask, softmax — lane i < 24 owns row i.
        // shuffles executed by ALL lanes (source lanes 24..47 must be active).
        float ev[NN];
        float m = -3.0e38f;
        const float f1i = fval;
        #pragma unroll
        for (int j = 0; j < NN; ++j) {
            float f2j = __shfl(fval, NN + j, 64);
            float e = f1i + f2j;
            e = (e > 0.f) ? e : ALPHA_ * e;
            e = ((amask >> j) & 1u) ? e : NEG_INF_;
            ev[j] = e;
            m = fmaxf(m, e);
        }
        float ssum = 0.f;
        #pragma unroll
        for (int j = 0; j < NN; ++j) { ev[j] = __expf(ev[j] - m); ssum += ev[j]; }
        const float inv = 1.f / ssum;
        if (lane < NN) {
            #pragma unroll
            for (int j = 0; j < NN; ++j)
                attn_s[(r * NN + lane) * 25 + j] = ev[j] * inv;
        }
        // wave-coherent: same wave wrote the attn_s rows it now reads
        // (LDS ops from one wave complete in order; indices may alias so the
        //  compiler won't reorder across them).

        // h' = attn @ Wh_row ; elu ; mean over i. lane = output channel h.
        float wcol[NN];
        #pragma unroll
        for (int j = 0; j < NN; ++j)
            wcol[j] = whs[(r * NN + j) * 65 + lane];
        float acc = 0.f;
        #pragma unroll
        for (int i = 0; i < NN; ++i) {
            const float* ar = attn_s + (r * NN + i) * 25;
            float hp = 0.f;
            #pragma unroll
            for (int j = 0; j < NN; ++j)
                hp += ar[j] * wcol[j];
            hp = (hp > 0.f) ? hp : (expm1f(hp));
            acc += hp;
        }
        out[(base + r) * HH + lane] = acc * (1.0f / 24.0f);
    }
}

// ---------------------------------------------------------------------------
extern "C" void kernel_launch(void* const* d_in, const int* in_sizes, int n_in,
                              void* d_out, int out_size, void* d_ws, size_t ws_size,
                              hipStream_t stream)
{
    const float* x   = (const float*)d_in[0];
    const int*   adj = (const int*)d_in[1];
    const float* Wp  = (const float*)d_in[2];
    const float* bp  = (const float*)d_in[3];
    const float* W   = (const float*)d_in[4];
    const float* a   = (const float*)d_in[5];
    float* out = (float*)d_out;

    float* WpWT = (float*)d_ws;                       // 1536*64 floats
    float* bpW  = WpWT + (size_t)CC * F_IN;           // 1536 floats

    // 98304 + 1536 = 99840 threads -> 390 blocks
    precompute_kernel<<<390, 256, 0, stream>>>(Wp, bp, W, WpWT, bpW);

    gat_main_kernel<<<BT_TOT / ROWS, 256, 0, stream>>>(x, adj, a, WpWT, bpW, out);
}

// Round 3
// 328.443 us; speedup vs baseline: 2.7726x; 2.7726x over previous
//
#include <hip/hip_runtime.h>
#include <hip/hip_bf16.h>

#define F_IN   64
#define NN     24
#define HH     64
#define CC     (NN * HH)      // 1536
#define ROWS   8
#define BT_TOT (16 * 2048)    // 32768
#define ALPHA_ 0.2f
#define NEG_INF_ -9.0e15f
#define WHP    68             // whs row pad (float4-aligned, breaks pow2 banks)
#define ATP    28             // attn row pad (float4-aligned)

// ---------------------------------------------------------------------------
// Precompute (k-major): WpWk[f*CC + c] = sum_m Wp[f, n*64+m] * W[m, j]
//                       bpW[c]         = sum_m bp[n*64+m]    * W[m, j]
// where c = n*64 + j.
// ---------------------------------------------------------------------------
__global__ __launch_bounds__(256) void precompute_kernel(
    const float* __restrict__ Wp,
    const float* __restrict__ bp,
    const float* __restrict__ W,
    float* __restrict__ WpWk,
    float* __restrict__ bpW)
{
    const int b = blockIdx.x;
    const int tid = threadIdx.x;
    if (b < 384) {                       // 384 blocks: 64 f x 6 c-chunks
        const int f = b / 6;
        const int c = (b % 6) * 256 + tid;
        const int n = c >> 6, j = c & 63;
        float s = 0.f;
        #pragma unroll 8
        for (int m = 0; m < 64; ++m)
            s += Wp[f * CC + n * 64 + m] * W[m * 64 + j];
        WpWk[f * CC + c] = s;
    } else {                             // 6 blocks: bpW (1536 entries)
        const int c = (b - 384) * 256 + tid;
        const int n = c >> 6, j = c & 63;
        float s = 0.f;
        #pragma unroll 8
        for (int m = 0; m < 64; ++m)
            s += bp[n * 64 + m] * W[m * 64 + j];
        bpW[c] = s;
    }
}

// ---------------------------------------------------------------------------
// Main fused kernel: 8 rows per block of 256 threads.
// ---------------------------------------------------------------------------
__global__ __launch_bounds__(256, 2) void gat_main_kernel(
    const float* __restrict__ x,
    const int* __restrict__ adj,
    const float* __restrict__ a_vec,
    const float* __restrict__ WpWk,
    const float* __restrict__ bpW,
    float* __restrict__ out)
{
    __shared__ float xs[ROWS * F_IN];            // 2 KB
    __shared__ float whs[ROWS * NN * WHP];       // 52224 B
    __shared__ float attn_s[ROWS * NN * ATP];    // 21504 B

    const int tid = threadIdx.x;
    const size_t base = (size_t)blockIdx.x * ROWS;

    // stage x rows (fp32, coalesced)
    for (int i = tid; i < ROWS * F_IN; i += 256)
        xs[i] = x[base * F_IN + i];
    __syncthreads();

    // ---------- Phase 2: Wh tile = x_tile @ WpW + bpW ----------
    // Thread owns 6 columns: {2*tid, 2*tid+1} + 512*p, p=0..2.
    // Weights stream k-major (coalesced float2); x broadcast from LDS.
    // 48 fp32 accumulators — no register-resident weight tile (round-2 spill fix).
    {
        float acc[3][2][ROWS];
        #pragma unroll
        for (int p = 0; p < 3; ++p)
            #pragma unroll
            for (int e = 0; e < 2; ++e)
                #pragma unroll
                for (int r = 0; r < ROWS; ++r) acc[p][e][r] = 0.f;

        const int c0 = 2 * tid;
        #pragma unroll 4
        for (int k2 = 0; k2 < 32; ++k2) {
            float2 xv[ROWS];
            #pragma unroll
            for (int r = 0; r < ROWS; ++r)
                xv[r] = *(const float2*)(xs + r * F_IN + 2 * k2);
            #pragma unroll
            for (int p = 0; p < 3; ++p) {
                const float2 w0 = *(const float2*)(WpWk + (size_t)(2 * k2) * CC + c0 + 512 * p);
                const float2 w1 = *(const float2*)(WpWk + (size_t)(2 * k2 + 1) * CC + c0 + 512 * p);
                #pragma unroll
                for (int r = 0; r < ROWS; ++r) {
                    acc[p][0][r] += w0.x * xv[r].x + w1.x * xv[r].y;
                    acc[p][1][r] += w0.y * xv[r].x + w1.y * xv[r].y;
                }
            }
        }
        #pragma unroll
        for (int p = 0; p < 3; ++p)
            #pragma unroll
            for (int e = 0; e < 2; ++e) {
                const int c = c0 + 512 * p + e;
                const float bb = bpW[c];
                const int n = c >> 6, j = c & 63;
                #pragma unroll
                for (int r = 0; r < ROWS; ++r)
                    whs[(r * NN + n) * WHP + j] = acc[p][e][r] + bb;
            }
    }
    __syncthreads();

    // ---------- Phase 3: attention + ELU + mean, one wave per 2 rows ----------
    const int lane = tid & 63;
    const int wid  = tid >> 6;

    // adjacency bitmask for lanes < 24 (tiny; L2-cached)
    unsigned amask = 0u;
    if (lane < NN) {
        #pragma unroll
        for (int j = 0; j < NN; ++j)
            amask |= (adj[lane * NN + j] > 0 ? 1u : 0u) << j;
    }

    for (int rr = 0; rr < 2; ++rr) {
        const int r = wid * 2 + rr;

        // f1 (lanes 0..23) / f2 (lanes 24..47): dot(Wh_row[n,:], a1/a2)
        float fval = 0.f;
        if (lane < 2 * NN) {
            const int which = (lane >= NN) ? 1 : 0;
            const int n = lane - which * NN;
            const float4* wh4 = (const float4*)(whs + (r * NN + n) * WHP);
            const float4* av4 = (const float4*)(a_vec + which * HH);
            #pragma unroll
            for (int kk = 0; kk < 16; ++kk) {
                const float4 w = wh4[kk];
                const float4 av = av4[kk];
                fval += w.x * av.x + w.y * av.y + w.z * av.z + w.w * av.w;
            }
        }

        // e-row, leaky relu, mask, softmax — lane i < 24 owns row i.
        // Shuffles executed by ALL lanes (source lanes 24..47 must be active).
        float ev[NN];
        float m = -3.0e38f;
        const float f1i = fval;
        #pragma unroll
        for (int j = 0; j < NN; ++j) {
            float f2j = __shfl(fval, NN + j, 64);
            float e = f1i + f2j;
            e = (e > 0.f) ? e : ALPHA_ * e;
            e = ((amask >> j) & 1u) ? e : NEG_INF_;
            ev[j] = e;
            m = fmaxf(m, e);
        }
        float ssum = 0.f;
        #pragma unroll
        for (int j = 0; j < NN; ++j) { ev[j] = __expf(ev[j] - m); ssum += ev[j]; }
        const float inv = 1.f / ssum;
        if (lane < NN) {
            #pragma unroll
            for (int j = 0; j < NN; ++j)
                attn_s[(r * NN + lane) * ATP + j] = ev[j] * inv;
        }
        // wave-coherent: the same wave wrote the attn_s rows it now reads.

        // h' = attn @ Wh_row ; elu ; mean over i. lane = output channel h.
        float wcol[NN];
        #pragma unroll
        for (int j = 0; j < NN; ++j)
            wcol[j] = whs[(r * NN + j) * WHP + lane];
        float acc3 = 0.f;
        #pragma unroll
        for (int i = 0; i < NN; ++i) {
            const float4* ar4 = (const float4*)(attn_s + (r * NN + i) * ATP);
            float hp = 0.f;
            #pragma unroll
            for (int q = 0; q < 6; ++q) {
                const float4 av = ar4[q];
                hp += av.x * wcol[4 * q] + av.y * wcol[4 * q + 1]
                    + av.z * wcol[4 * q + 2] + av.w * wcol[4 * q + 3];
            }
            hp = (hp > 0.f) ? hp : (__expf(hp) - 1.f);   // ELU; arg<=0, no overflow
            acc3 += hp;
        }
        out[(base + r) * HH + lane] = acc3 * (1.0f / 24.0f);
    }
}

// ---------------------------------------------------------------------------
extern "C" void kernel_launch(void* const* d_in, const int* in_sizes, int n_in,
                              void* d_out, int out_size, void* d_ws, size_t ws_size,
                              hipStream_t stream)
{
    const float* x   = (const float*)d_in[0];
    const int*   adj = (const int*)d_in[1];
    const float* Wp  = (const float*)d_in[2];
    const float* bp  = (const float*)d_in[3];
    const float* W   = (const float*)d_in[4];
    const float* a   = (const float*)d_in[5];
    float* out = (float*)d_out;

    float* WpWk = (float*)d_ws;                       // 64*1536 floats (k-major)
    float* bpW  = WpWk + (size_t)F_IN * CC;           // 1536 floats

    precompute_kernel<<<390, 256, 0, stream>>>(Wp, bp, W, WpWk, bpW);
    gat_main_kernel<<<BT_TOT / ROWS, 256, 0, stream>>>(x, adj, a, WpWk, bpW, out);
}

// Round 4
// 227.649 us; speedup vs baseline: 4.0002x; 1.4428x over previous
//
#include <hip/hip_runtime.h>
#include <hip/hip_bf16.h>

#define F_IN   64
#define NN     24
#define HH     64
#define CC     (NN * HH)      // 1536
#define ROWS   8
#define BT_TOT (16 * 2048)    // 32768
#define ALPHA_ 0.2f
#define NEG_INF_ -9.0e15f
#define WHP    68             // whs row pad (fp32, float4-aligned)
#define ATP    28             // attn row pad (float4-aligned)
#define XSP    72             // xs16 row stride in shorts (144 B, 16 B-aligned)
#define NTILE  96             // 1536 / 16 column tiles

typedef short bf16x8 __attribute__((ext_vector_type(8)));
typedef float f32x4  __attribute__((ext_vector_type(4)));

// fp32 -> bf16 bits, round-to-nearest-even (no NaN inputs here)
__device__ __forceinline__ short f2bf(float f) {
    unsigned u = __float_as_uint(f);
    return (short)((u + 0x7FFFu + ((u >> 16) & 1u)) >> 16);
}

// ---------------------------------------------------------------------------
// Precompute: fused weight WpW[k][c] = sum_m Wp[k, n*64+m] * W[m, j]
// (c = n*64+j), emitted pre-packed in MFMA B-fragment layout, bf16:
//   Bpk[((t*2 + s)*64 + lane)*8 + jj]  holds  WpW[k][c]
//   with k = s*32 + (lane>>4)*8 + jj,  c = t*16 + (lane&15).
// Plus bpW[c] (fp32 bias after W).
// ---------------------------------------------------------------------------
__global__ __launch_bounds__(256) void precompute_kernel(
    const float* __restrict__ Wp,
    const float* __restrict__ bp,
    const float* __restrict__ W,
    short* __restrict__ Bpk,
    float* __restrict__ bpW)
{
    const int b = blockIdx.x;
    const int tid = threadIdx.x;
    if (b < 384) {                       // 384*256 = 98304 packed values
        const int u  = b * 256 + tid;
        const int jj = u & 7;
        const int l  = (u >> 3) & 63;
        const int s  = (u >> 9) & 1;
        const int t  = u >> 10;
        const int k  = s * 32 + ((l >> 4) << 3) + jj;
        const int c  = t * 16 + (l & 15);
        const int n  = c >> 6, jc = c & 63;
        float v = 0.f;
        #pragma unroll 8
        for (int m = 0; m < 64; ++m)
            v += Wp[k * CC + n * 64 + m] * W[m * 64 + jc];
        Bpk[u] = f2bf(v);
    } else {                             // 6 blocks: bpW (1536 entries)
        const int c = (b - 384) * 256 + tid;
        const int n = c >> 6, jc = c & 63;
        float s = 0.f;
        #pragma unroll 8
        for (int m = 0; m < 64; ++m)
            s += bp[n * 64 + m] * W[m * 64 + jc];
        bpW[c] = s;
    }
}

// ---------------------------------------------------------------------------
// Main fused kernel: 8 rows per block of 256 threads (4 waves).
// ---------------------------------------------------------------------------
__global__ __launch_bounds__(256, 2) void gat_main_kernel(
    const float* __restrict__ x,
    const int* __restrict__ adj,
    const float* __restrict__ a_vec,
    const short* __restrict__ Bpk,
    const float* __restrict__ bpW,
    float* __restrict__ out)
{
    __shared__ __align__(16) short xs16[16 * XSP];   // 2304 B (rows 8..15 zero)
    __shared__ float whs[ROWS * NN * WHP];           // 52224 B
    __shared__ float attn_s[ROWS * NN * ATP];        // 21504 B

    const int tid  = threadIdx.x;
    const int lane = tid & 63;
    const int wid  = tid >> 6;
    const size_t base = (size_t)blockIdx.x * ROWS;

    // stage x rows as bf16 (A-operand); zero the M-padding rows 8..15
    for (int i = tid; i < 512; i += 256) {
        int r = i >> 6, k = i & 63;
        xs16[r * XSP + k] = f2bf(x[base * F_IN + i]);
        xs16[(8 + r) * XSP + k] = 0;
    }
    __syncthreads();

    // ---------- Phase 2 (MFMA): Wh tile = x_tile @ WpW + bpW ----------
    // Wave wid owns 24 column-tiles (384 cols). A-frag: lane = (quad, lm),
    // A[m = lm][k = quad*8 + j] read straight from xs16. B pre-packed in Bpk.
    {
        const int quad = lane >> 4;
        const int lm   = lane & 15;
        const bf16x8 a0 = *(const bf16x8*)(xs16 + lm * XSP + quad * 8);
        const bf16x8 a1 = *(const bf16x8*)(xs16 + lm * XSP + 32 + quad * 8);
        #pragma unroll 6
        for (int tt = 0; tt < 24; ++tt) {
            const int t = wid * 24 + tt;
            const short* bp0 = Bpk + ((size_t)(t * 2) * 64 + lane) * 8;
            const bf16x8 b0 = *(const bf16x8*)bp0;          // 16 B coalesced
            const bf16x8 b1 = *(const bf16x8*)(bp0 + 64 * 8);
            f32x4 acc = {0.f, 0.f, 0.f, 0.f};
            acc = __builtin_amdgcn_mfma_f32_16x16x32_bf16(a0, b0, acc, 0, 0, 0);
            acc = __builtin_amdgcn_mfma_f32_16x16x32_bf16(a1, b1, acc, 0, 0, 0);
            // C/D: col = lane&15, row = quad*4 + reg.  Rows 8..15 are padding.
            if (quad < 2) {
                const int c = t * 16 + lm;
                const int n = c >> 6, j = c & 63;
                const float bb = bpW[c];
                #pragma unroll
                for (int i = 0; i < 4; ++i)
                    whs[((quad * 4 + i) * NN + n) * WHP + j] = acc[i] + bb;
            }
        }
    }
    __syncthreads();

    // ---------- Phase 3: attention + ELU + mean, one wave per 2 rows ----------
    // adjacency bitmask for lanes < 24 (tiny; L2-cached)
    unsigned amask = 0u;
    if (lane < NN) {
        #pragma unroll
        for (int j = 0; j < NN; ++j)
            amask |= (adj[lane * NN + j] > 0 ? 1u : 0u) << j;
    }

    for (int rr = 0; rr < 2; ++rr) {
        const int r = wid * 2 + rr;

        // f1 (lanes 0..23) / f2 (lanes 24..47): dot(Wh_row[n,:], a1/a2)
        float fval = 0.f;
        if (lane < 2 * NN) {
            const int which = (lane >= NN) ? 1 : 0;
            const int n = lane - which * NN;
            const float4* wh4 = (const float4*)(whs + (r * NN + n) * WHP);
            const float4* av4 = (const float4*)(a_vec + which * HH);
            #pragma unroll
            for (int kk = 0; kk < 16; ++kk) {
                const float4 w = wh4[kk];
                const float4 av = av4[kk];
                fval += w.x * av.x + w.y * av.y + w.z * av.z + w.w * av.w;
            }
        }

        // e-row, leaky relu, mask, softmax — lane i < 24 owns row i.
        // Shuffles executed by ALL lanes (source lanes 24..47 must be active).
        float ev[NN];
        float m = -3.0e38f;
        const float f1i = fval;
        #pragma unroll
        for (int j = 0; j < NN; ++j) {
            float f2j = __shfl(fval, NN + j, 64);
            float e = f1i + f2j;
            e = (e > 0.f) ? e : ALPHA_ * e;
            e = ((amask >> j) & 1u) ? e : NEG_INF_;
            ev[j] = e;
            m = fmaxf(m, e);
        }
        float ssum = 0.f;
        #pragma unroll
        for (int j = 0; j < NN; ++j) { ev[j] = __expf(ev[j] - m); ssum += ev[j]; }
        const float inv = 1.f / ssum;
        if (lane < NN) {
            #pragma unroll
            for (int j = 0; j < NN; ++j)
                attn_s[(r * NN + lane) * ATP + j] = ev[j] * inv;
        }
        // wave-coherent: the same wave wrote the attn_s rows it now reads.

        // h' = attn @ Wh_row ; elu ; mean over i. lane = output channel h.
        float wcol[NN];
        #pragma unroll
        for (int j = 0; j < NN; ++j)
            wcol[j] = whs[(r * NN + j) * WHP + lane];
        float acc3 = 0.f;
        #pragma unroll
        for (int i = 0; i < NN; ++i) {
            const float4* ar4 = (const float4*)(attn_s + (r * NN + i) * ATP);
            float hp = 0.f;
            #pragma unroll
            for (int q = 0; q < 6; ++q) {
                const float4 av = ar4[q];
                hp += av.x * wcol[4 * q] + av.y * wcol[4 * q + 1]
                    + av.z * wcol[4 * q + 2] + av.w * wcol[4 * q + 3];
            }
            hp = (hp > 0.f) ? hp : (__expf(hp) - 1.f);   // ELU; arg <= 0
            acc3 += hp;
        }
        out[(base + r) * HH + lane] = acc3 * (1.0f / 24.0f);
    }
}

// ---------------------------------------------------------------------------
extern "C" void kernel_launch(void* const* d_in, const int* in_sizes, int n_in,
                              void* d_out, int out_size, void* d_ws, size_t ws_size,
                              hipStream_t stream)
{
    const float* x   = (const float*)d_in[0];
    const int*   adj = (const int*)d_in[1];
    const float* Wp  = (const float*)d_in[2];
    const float* bp  = (const float*)d_in[3];
    const float* W   = (const float*)d_in[4];
    const float* a   = (const float*)d_in[5];
    float* out = (float*)d_out;

    short* Bpk = (short*)d_ws;                        // 98304 bf16 (196.6 KB)
    float* bpW = (float*)(Bpk + (size_t)NTILE * 2 * 64 * 8);  // 1536 fp32

    precompute_kernel<<<390, 256, 0, stream>>>(Wp, bp, W, Bpk, bpW);
    gat_main_kernel<<<BT_TOT / ROWS, 256, 0, stream>>>(x, adj, a, Bpk, bpW, out);
}